// Round 1
// baseline (153.928 us; speedup 1.0000x reference)
//
#include <hip/hip_runtime.h>
#include <math.h>

#define T_FR 400
#define B_SZ 8
#define NH   32
#define HOP  240
#define PI_F 3.14159265358979323846f
#define TWO_PI_F 6.28318530717958647692f
#define TWO_PI_D 6.283185307179586476925287

enum { ACT_NONE=0, ACT_RELU=1, ACT_BNRELU=2, ACT_SIG=3, ACT_TANH=4 };

// ---------------- mean of f0 + init wmax ----------------
__global__ __launch_bounds__(256)
void mean_init_k(const float* __restrict__ f0, float* __restrict__ mean_out,
                 unsigned int* __restrict__ wmax)
{
    __shared__ double sm[256];
    double s = 0.0;
    for (int i = threadIdx.x; i < B_SZ*T_FR; i += 256) s += (double)f0[i];
    sm[threadIdx.x] = s;
    __syncthreads();
    for (int off = 128; off > 0; off >>= 1) {
        if ((int)threadIdx.x < off) sm[threadIdx.x] += sm[threadIdx.x + off];
        __syncthreads();
    }
    if (threadIdx.x == 0) mean_out[0] = (float)(sm[0] / (double)(B_SZ*T_FR));
    if (threadIdx.x < B_SZ) wmax[threadIdx.x] = 0u;
}

// ---------------- per-(b,h) frame-level prefix scan ----------------
__device__ inline double shfl_up_dbl(double x, int off)
{
    long long v = __double_as_longlong(x);
    int lo = (int)(v & 0xffffffffLL);
    int hi = (int)(v >> 32);
    lo = __shfl_up(lo, off);
    hi = __shfl_up(hi, off);
    return __longlong_as_double(((long long)hi << 32) | (unsigned int)(unsigned)lo);
}

__global__ __launch_bounds__(256)
void f0_scan_k(const float* __restrict__ f0, const float* __restrict__ voicing,
               const float* __restrict__ mean_p,
               float* __restrict__ inc_out, float* __restrict__ pref_out)
{
    const int wid  = (int)(blockIdx.x * 4 + (threadIdx.x >> 6)); // 0..255 rows (b,h)
    const int lane = (int)(threadIdx.x & 63);
    const int b = wid >> 5;
    const int h = wid & 31;
    const float n = (float)(h + 1);
    const float mean = mean_p[0];
    const float C = (float)(2.0 * 3.14159265358979323846 / 22050.0);

    float inc_loc[7];
    double local = 0.0;
    const int t0 = lane * 7;
    #pragma unroll
    for (int j = 0; j < 7; ++j) {
        int t = t0 + j;
        float iv = 0.f;
        if (t < T_FR) {
            float x  = f0[b*T_FR + t];
            float vv = voicing[b*T_FR + t];
            float midi = 440.0f * exp2f((x - 69.0f) / 12.0f);
            float fz = (mean < 0.f) ? expf(x) : ((mean < 50.f) ? midi : x);
            fz = fminf(fmaxf(fz, 50.f), 4000.f);
            fz = fz * vv + 100.f * (1.f - vv);
            float hf = fz * n;
            iv = hf * C;
            iv = fminf(fmaxf(iv, -PI_F), PI_F);
        }
        inc_loc[j] = iv;
        local += (double)iv;
    }
    local *= 240.0;   // frame sum contribution of this lane's frames

    // inclusive wave scan (double)
    double inc_sc = local;
    for (int off = 1; off < 64; off <<= 1) {
        double o = shfl_up_dbl(inc_sc, off);
        if (lane >= off) inc_sc += o;
    }
    double run = inc_sc - local;  // exclusive prefix for this lane's first frame

    #pragma unroll
    for (int j = 0; j < 7; ++j) {
        int t = t0 + j;
        if (t < T_FR) {
            inc_out[wid*T_FR + t]  = inc_loc[j];
            pref_out[wid*T_FR + t] = (float)fmod(run, TWO_PI_D);
            run += (double)inc_loc[j] * 240.0;
        }
    }
}

// ---------------- generic 3-tap conv1d, 4 cout per thread ----------------
template<int CIN1, int CIN2, int ACT>
__global__ __launch_bounds__(64)
void conv3_k(const float* __restrict__ x1, const float* __restrict__ x2,
             const float* __restrict__ w, const float* __restrict__ bias,
             const float* __restrict__ g, const float* __restrict__ be,
             const float* __restrict__ mn, const float* __restrict__ vr,
             const float* __restrict__ voiced,
             float* __restrict__ y, int Cout)
{
    const int t   = (int)(blockIdx.x * 64 + threadIdx.x);
    const bool ok = (t < T_FR);
    const int tt  = ok ? t : 0;
    const int co0 = (int)blockIdx.y * 4;
    const int b   = (int)blockIdx.z;
    const int CIN = CIN1 + CIN2;
    const bool hasm = ok && (t > 0);
    const bool hasp = ok && (t < T_FR - 1);

    float acc[4];
    #pragma unroll
    for (int j = 0; j < 4; ++j) acc[j] = bias[co0 + j];

    {
        const float* xb = x1 + (size_t)b * CIN1 * T_FR + tt;
        #pragma unroll 4
        for (int ci = 0; ci < CIN1; ++ci) {
            float xm = hasm ? xb[ci*T_FR - 1] : 0.f;
            float xc = xb[ci*T_FR];
            float xp = hasp ? xb[ci*T_FR + 1] : 0.f;
            #pragma unroll
            for (int j = 0; j < 4; ++j) {
                const float* wr = w + ((size_t)(co0 + j) * CIN + ci) * 3;
                acc[j] = fmaf(xm, wr[0], acc[j]);
                acc[j] = fmaf(xc, wr[1], acc[j]);
                acc[j] = fmaf(xp, wr[2], acc[j]);
            }
        }
    }
    if constexpr (CIN2 > 0) {
        const float* xb = x2 + (size_t)b * CIN2 * T_FR + tt;
        #pragma unroll 4
        for (int ci = 0; ci < CIN2; ++ci) {
            float xm = hasm ? xb[ci*T_FR - 1] : 0.f;
            float xc = xb[ci*T_FR];
            float xp = hasp ? xb[ci*T_FR + 1] : 0.f;
            #pragma unroll
            for (int j = 0; j < 4; ++j) {
                const float* wr = w + ((size_t)(co0 + j) * CIN + (CIN1 + ci)) * 3;
                acc[j] = fmaf(xm, wr[0], acc[j]);
                acc[j] = fmaf(xc, wr[1], acc[j]);
                acc[j] = fmaf(xp, wr[2], acc[j]);
            }
        }
    }

    if (ok) {
        #pragma unroll
        for (int j = 0; j < 4; ++j) {
            int co = co0 + j;
            float a = acc[j];
            float val;
            if (ACT == ACT_BNRELU) {
                float scale = g[co] * rsqrtf(vr[co] + 1e-5f);
                a = (a - mn[co]) * scale + be[co];
                val = fmaxf(a, 0.f);
            } else if (ACT == ACT_RELU) {
                val = fmaxf(a, 0.f);
            } else if (ACT == ACT_SIG) {
                float sg = 1.f / (1.f + expf(-a));
                val = sg * voiced[b*T_FR + t] + 1e-8f;
            } else if (ACT == ACT_TANH) {
                val = tanhf(a);
            } else {
                val = a;
            }
            y[((size_t)b * Cout + co) * T_FR + t] = val;
        }
    }
}

// ---------------- harmonic synthesis + per-batch |max| ----------------
__global__ __launch_bounds__(256)
void synth_k(const float* __restrict__ inc, const float* __restrict__ pref,
             const float* __restrict__ amps, const float* __restrict__ phases,
             float* __restrict__ wave, unsigned int* __restrict__ wmax)
{
    const int s = (int)(blockIdx.x * 256 + threadIdx.x);    // 0..767999
    const int b = s / (T_FR * HOP);
    const int i = s - b * (T_FR * HOP);
    const int t = i / HOP;
    const int k = i - t * HOP;
    const float kf = (float)(k + 1);

    float acc = 0.f;
    const int base = (b * NH) * T_FR + t;
    #pragma unroll 8
    for (int h = 0; h < NH; ++h) {
        const int r = base + h * T_FR;
        float phase = fmaf(kf, inc[r], pref[r]) + phases[r] * PI_F;
        float tp = fmodf(phase, TWO_PI_F);
        acc = fmaf(amps[r], __sinf(tp), acc);
    }
    wave[s] = acc;

    float a = fabsf(acc);
    #pragma unroll
    for (int off = 32; off > 0; off >>= 1) a = fmaxf(a, __shfl_down(a, off));
    __shared__ float sm4[4];
    const int lane = (int)(threadIdx.x & 63);
    const int wv   = (int)(threadIdx.x >> 6);
    if (lane == 0) sm4[wv] = a;
    __syncthreads();
    if (threadIdx.x == 0) {
        float m = fmaxf(fmaxf(sm4[0], sm4[1]), fmaxf(sm4[2], sm4[3]));
        atomicMax(&wmax[b], __float_as_uint(m));   // |wave| >= 0 so uint-bit max == float max
    }
}

__global__ __launch_bounds__(256)
void norm_k(const float* __restrict__ wave, const unsigned int* __restrict__ wmax,
            float* __restrict__ out)
{
    const int s = (int)(blockIdx.x * 256 + threadIdx.x);
    const int b = s / (T_FR * HOP);
    float wm = fmaxf(__uint_as_float(wmax[b]), 1e-8f);
    out[s] = tanhf(wave[s] / wm);
}

// ---------------- launch ----------------
extern "C" void kernel_launch(void* const* d_in, const int* in_sizes, int n_in,
                              void* d_out, int out_size, void* d_ws, size_t ws_size,
                              hipStream_t stream)
{
    const float* mel  = (const float*)d_in[0];
    const float* f0   = (const float*)d_in[1];
    const float* voi  = (const float*)d_in[2];
    const float* w_f1 = (const float*)d_in[3];  const float* b_f1 = (const float*)d_in[4];
    const float* w_f2 = (const float*)d_in[5];  const float* b_f2 = (const float*)d_in[6];
    const float* w_a1 = (const float*)d_in[7];  const float* b_a1 = (const float*)d_in[8];
    const float* g1   = (const float*)d_in[9];  const float* be1  = (const float*)d_in[10];
    const float* m1   = (const float*)d_in[11]; const float* v1   = (const float*)d_in[12];
    const float* w_a2 = (const float*)d_in[13]; const float* b_a2 = (const float*)d_in[14];
    const float* g2   = (const float*)d_in[15]; const float* be2  = (const float*)d_in[16];
    const float* m2   = (const float*)d_in[17]; const float* v2   = (const float*)d_in[18];
    const float* w_a3 = (const float*)d_in[19]; const float* b_a3 = (const float*)d_in[20];
    const float* w_p1 = (const float*)d_in[21]; const float* b_p1 = (const float*)d_in[22];
    const float* w_p2 = (const float*)d_in[23]; const float* b_p2 = (const float*)d_in[24];

    float* wsf = (float*)d_ws;
    float* meanp = wsf + 0;
    unsigned int* wmax = (unsigned int*)(wsf + 8);
    float* F1   = wsf + 16;                 // (8,16,400)
    float* F2   = F1   + 8*16*400;          // (8,16,400)
    float* H1   = F2   + 8*16*400;          // (8,128,400)
    float* H2   = H1   + 8*128*400;         // (8,128,400)
    float* AMP  = H2   + 8*128*400;         // (8,32,400)
    float* P1   = AMP  + 8*32*400;          // (8,64,400)
    float* PH   = P1   + 8*64*400;          // (8,32,400)
    float* INC  = PH   + 8*32*400;          // (8,32,400)
    float* PREF = INC  + 8*32*400;          // (8,32,400)
    float* WAVE = PREF + 8*32*400;          // (8,96000)

    mean_init_k<<<1, 256, 0, stream>>>(f0, meanp, wmax);
    f0_scan_k<<<64, 256, 0, stream>>>(f0, voi, meanp, INC, PREF);

    conv3_k<1,0,ACT_RELU><<<dim3(7,4,8), 64, 0, stream>>>(
        f0, nullptr, w_f1, b_f1, nullptr,nullptr,nullptr,nullptr, nullptr, F1, 16);
    conv3_k<16,0,ACT_RELU><<<dim3(7,4,8), 64, 0, stream>>>(
        F1, nullptr, w_f2, b_f2, nullptr,nullptr,nullptr,nullptr, nullptr, F2, 16);
    conv3_k<80,0,ACT_BNRELU><<<dim3(7,32,8), 64, 0, stream>>>(
        mel, nullptr, w_a1, b_a1, g1, be1, m1, v1, nullptr, H1, 128);
    conv3_k<128,0,ACT_BNRELU><<<dim3(7,32,8), 64, 0, stream>>>(
        H1, nullptr, w_a2, b_a2, g2, be2, m2, v2, nullptr, H2, 128);
    conv3_k<128,0,ACT_SIG><<<dim3(7,8,8), 64, 0, stream>>>(
        H2, nullptr, w_a3, b_a3, nullptr,nullptr,nullptr,nullptr, voi, AMP, 32);
    conv3_k<80,16,ACT_RELU><<<dim3(7,16,8), 64, 0, stream>>>(
        mel, F2, w_p1, b_p1, nullptr,nullptr,nullptr,nullptr, nullptr, P1, 64);
    conv3_k<64,0,ACT_TANH><<<dim3(7,8,8), 64, 0, stream>>>(
        P1, nullptr, w_p2, b_p2, nullptr,nullptr,nullptr,nullptr, nullptr, PH, 32);

    synth_k<<<3000, 256, 0, stream>>>(INC, PREF, AMP, PH, WAVE, wmax);
    norm_k<<<3000, 256, 0, stream>>>(WAVE, wmax, (float*)d_out);
}